// Round 9
// baseline (232.134 us; speedup 1.0000x reference)
//
#include <hip/hip_runtime.h>

#define NN 100000
#define EE 1200000
#define NB 391          // ceil(NN/256) buckets of 256 nodes
#define EPB 4096        // edges per block in binning kernels
#define BIN_BLK 293     // ceil(EE/EPB)

typedef _Float16 half4 __attribute__((ext_vector_type(4)));
typedef _Float16 half8 __attribute__((ext_vector_type(8)));
typedef float    f32x4 __attribute__((ext_vector_type(4)));

// ---------------- bucket histogram (LDS-aggregated) ----------------
__global__ __launch_bounds__(256) void k_binhist(const int* __restrict__ col, int* __restrict__ bcnt) {
  __shared__ int lh[NB];
  int t = threadIdx.x;
  for (int i = t; i < NB; i += 256) lh[i] = 0;
  __syncthreads();
  int base = blockIdx.x * EPB;
  #pragma unroll
  for (int i = 0; i < 16; ++i) {
    int e = base + i * 256 + t;
    if (e < EE) atomicAdd(&lh[col[e] >> 8], 1);
  }
  __syncthreads();
  for (int i = t; i < NB; i += 256) {
    int v = lh[i];
    if (v) atomicAdd(&bcnt[i], v);
  }
}

// ---------------- scan bucket counts -> bptr, init cursors ----------------
__global__ __launch_bounds__(512) void k_binscan(const int* __restrict__ bcnt, int* __restrict__ bptr,
                                                 int* __restrict__ bcur, int* __restrict__ row_ptr) {
  __shared__ int sm[512];
  int t = threadIdx.x;
  int v = (t < NB) ? bcnt[t] : 0;
  sm[t] = v;
  __syncthreads();
  for (int off = 1; off < 512; off <<= 1) {
    int u = (t >= off) ? sm[t - off] : 0;
    __syncthreads();
    sm[t] += u;
    __syncthreads();
  }
  int excl = sm[t] - v;
  if (t < NB) { bptr[t] = excl; bcur[t] = excl; }
  if (t == 0) { bptr[NB] = EE; row_ptr[NN] = EE; }
}

// ---------------- bucket fill: binned[p] = (row<<8)|(col&255), grouped by bucket ----------------
__global__ __launch_bounds__(256) void k_binfill(const int* __restrict__ row, const int* __restrict__ col,
                                                 int* __restrict__ bcur, int* __restrict__ binned) {
  __shared__ int lh[NB];
  __shared__ int lbase[NB];
  int t = threadIdx.x;
  for (int i = t; i < NB; i += 256) lh[i] = 0;
  __syncthreads();
  int base = blockIdx.x * EPB;
  #pragma unroll
  for (int i = 0; i < 16; ++i) {
    int e = base + i * 256 + t;
    if (e < EE) atomicAdd(&lh[col[e] >> 8], 1);
  }
  __syncthreads();
  // reserve contiguous global ranges per bucket; reset LDS cursors
  for (int i = t; i < NB; i += 256) {
    int v = lh[i];
    lbase[i] = v ? atomicAdd(&bcur[i], v) : 0;
  }
  __syncthreads();
  for (int i = t; i < NB; i += 256) lh[i] = 0;   // reuse as local cursor
  __syncthreads();
  #pragma unroll
  for (int i = 0; i < 16; ++i) {
    int e = base + i * 256 + t;
    if (e < EE) {
      int c = col[e];
      int b = c >> 8;
      int p = lbase[b] + atomicAdd(&lh[b], 1);
      binned[p] = (row[e] << 8) | (c & 255);
    }
  }
}

// ---------------- per-bucket CSR build: row_ptr, src, dinv (all bucket-local) ----------------
__global__ __launch_bounds__(256) void k_build2(const int* __restrict__ binned, const int* __restrict__ bptr,
                                                int* __restrict__ row_ptr, int* __restrict__ src,
                                                float* __restrict__ dinv) {
  __shared__ int cnt[256];
  __shared__ int sm[256];
  __shared__ int cur[256];
  int t = threadIdx.x;
  int b = blockIdx.x;
  int nb0 = b << 8;
  int nnode = NN - nb0 < 256 ? NN - nb0 : 256;
  int ebeg = bptr[b], eend = bptr[b + 1];
  cnt[t] = 0;
  __syncthreads();
  for (int e = ebeg + t; e < eend; e += 256)
    atomicAdd(&cnt[binned[e] & 255], 1);
  __syncthreads();
  int v = cnt[t];
  sm[t] = v;
  __syncthreads();
  for (int off = 1; off < 256; off <<= 1) {
    int u = (t >= off) ? sm[t - off] : 0;
    __syncthreads();
    sm[t] += u;
    __syncthreads();
  }
  int excl = sm[t] - v;
  if (t < nnode) {
    row_ptr[nb0 + t] = ebeg + excl;
    dinv[nb0 + t] = rsqrtf((float)v + 1.0f);   // deg = in-count + self-loop
  }
  cur[t] = excl;
  __syncthreads();
  for (int e = ebeg + t; e < eend; e += 256) {
    int rc = binned[e];
    int cl = rc & 255;
    int p = ebeg + atomicAdd(&cur[cl], 1);
    src[p] = rc >> 8;
  }
}

// ---------------- GEMM1 (MFMA f16): g = fp16((x @ W1) * dinv[row]) ----------------
// 64 rows/block, 4 waves; wave w -> rows w*16..w*16+15, all 64 cols (4 n-tiles), K=128 (4 k-steps).
__global__ __launch_bounds__(256) void k_gemm1(const float* __restrict__ x, const float* __restrict__ W,
                                               const float* __restrict__ dinv, _Float16* __restrict__ g) {
  __shared__ _Float16 xh[64 * 136];   // 17.4 KB
  __shared__ _Float16 Wt[64 * 136];   // 17.4 KB, transposed: Wt[n][k]
  const int t = threadIdx.x;
  const int row0 = blockIdx.x * 64;

  // stage W transposed -> f16
  #pragma unroll
  for (int p = 0; p < 8; ++p) {
    int idx = t + p * 256;
    int k = idx >> 4;
    int n4 = (idx & 15) << 2;
    float4 v = *reinterpret_cast<const float4*>(&W[k * 64 + n4]);
    Wt[(n4 + 0) * 136 + k] = (_Float16)v.x;
    Wt[(n4 + 1) * 136 + k] = (_Float16)v.y;
    Wt[(n4 + 2) * 136 + k] = (_Float16)v.z;
    Wt[(n4 + 3) * 136 + k] = (_Float16)v.w;
  }
  // stage x rows -> f16
  #pragma unroll
  for (int p = 0; p < 4; ++p) {
    int idx = t + p * 256;          // 0..1023
    int r = idx >> 4;               // 0..63
    int k8 = idx & 15;              // 8-half group
    int grow = row0 + r;
    half8 h = {0, 0, 0, 0, 0, 0, 0, 0};
    if (grow < NN) {
      float4 a0 = *reinterpret_cast<const float4*>(&x[(size_t)grow * 128 + k8 * 8]);
      float4 a1 = *reinterpret_cast<const float4*>(&x[(size_t)grow * 128 + k8 * 8 + 4]);
      h[0] = (_Float16)a0.x; h[1] = (_Float16)a0.y; h[2] = (_Float16)a0.z; h[3] = (_Float16)a0.w;
      h[4] = (_Float16)a1.x; h[5] = (_Float16)a1.y; h[6] = (_Float16)a1.z; h[7] = (_Float16)a1.w;
    }
    *reinterpret_cast<half8*>(&xh[r * 136 + k8 * 8]) = h;
  }
  __syncthreads();

  const int w = t >> 6;      // wave 0..3
  const int l = t & 63;
  const int lrow = l & 15;   // A row / B col / C col
  const int kg = l >> 4;     // k-group 0..3

  f32x4 z = {0.0f, 0.0f, 0.0f, 0.0f};
  f32x4 acc[4];
  acc[0] = z; acc[1] = z; acc[2] = z; acc[3] = z;

  const _Float16* xb = &xh[(w * 16 + lrow) * 136 + kg * 8];
  #pragma unroll
  for (int s = 0; s < 4; ++s) {     // K=128, 32 per step
    half8 a = *reinterpret_cast<const half8*>(xb + s * 32);
    #pragma unroll
    for (int nt = 0; nt < 4; ++nt) {
      half8 b = *reinterpret_cast<const half8*>(&Wt[(nt * 16 + lrow) * 136 + kg * 8 + s * 32]);
      acc[nt] = __builtin_amdgcn_mfma_f32_16x16x32_f16(a, b, acc[nt], 0, 0, 0);
    }
  }

  // epilogue: C/D layout col=lane&15, row=(lane>>4)*4+reg (m89-verified)
  float dv[4];
  #pragma unroll
  for (int r = 0; r < 4; ++r) {
    int grow = row0 + w * 16 + kg * 4 + r;
    dv[r] = (grow < NN) ? dinv[grow] : 0.0f;
  }
  #pragma unroll
  for (int nt = 0; nt < 4; ++nt)
    #pragma unroll
    for (int r = 0; r < 4; ++r) {
      int grow = row0 + w * 16 + kg * 4 + r;
      if (grow < NN)
        g[(size_t)grow * 64 + nt * 16 + lrow] = (_Float16)(acc[nt][r] * dv[r]);
    }
}

// ---------------- gather1 + fused layer-2 GEMM ----------------
// Phase 1: hid_row = lrelu((g[c]+Σg[src])·dinv[c] + b1)  -> LDS (f32)
// Phase 2: g2[c] = fp16((hid_row @ W2) · dinv[c])         (64x40 row-local mini-GEMM)
__global__ __launch_bounds__(256) void k_gather1f(const int* __restrict__ row_ptr, const int* __restrict__ src,
                                                  const _Float16* __restrict__ g, const float* __restrict__ dinv,
                                                  const float* __restrict__ b1, const float* __restrict__ W2,
                                                  _Float16* __restrict__ g2) {
  __shared__ float hidS[16 * 68];    // 16 nodes x 64 feats, stride 68 (bank-staggered)
  __shared__ float Ws2[2576];        // W2 [64][40] flat + zero pad to 2576
  int t = threadIdx.x;
  // stage W2 (640 float4) + zero pad
  if (t < 16) Ws2[2560 + t] = 0.0f;
  for (int i = t; i < 640; i += 256)
    *reinterpret_cast<float4*>(&Ws2[i * 4]) = *reinterpret_cast<const float4*>(&W2[i * 4]);

  int nl = t >> 4;                   // local node 0..15
  int node = blockIdx.x * 16 + nl;   // NN = 6250*16 exactly
  int q = (t & 15) << 2;
  bool valid = node < NN;
  float dvv = 0.0f;
  float4 o = make_float4(0.f, 0.f, 0.f, 0.f);
  if (valid) {
    int beg = row_ptr[node], end = row_ptr[node + 1];
    half4 sv = *reinterpret_cast<const half4*>(&g[(size_t)node * 64 + q]);   // self loop
    float4 acc = make_float4((float)sv.x, (float)sv.y, (float)sv.z, (float)sv.w);
    int e = beg;
    for (; e + 3 < end; e += 4) {
      int s0 = src[e], s1 = src[e + 1], s2 = src[e + 2], s3 = src[e + 3];
      half4 v0 = *reinterpret_cast<const half4*>(&g[(size_t)s0 * 64 + q]);
      half4 v1 = *reinterpret_cast<const half4*>(&g[(size_t)s1 * 64 + q]);
      half4 v2 = *reinterpret_cast<const half4*>(&g[(size_t)s2 * 64 + q]);
      half4 v3 = *reinterpret_cast<const half4*>(&g[(size_t)s3 * 64 + q]);
      acc.x += ((float)v0.x + (float)v1.x) + ((float)v2.x + (float)v3.x);
      acc.y += ((float)v0.y + (float)v1.y) + ((float)v2.y + (float)v3.y);
      acc.z += ((float)v0.z + (float)v1.z) + ((float)v2.z + (float)v3.z);
      acc.w += ((float)v0.w + (float)v1.w) + ((float)v2.w + (float)v3.w);
    }
    for (; e < end; ++e) {
      int s0 = src[e];
      half4 v0 = *reinterpret_cast<const half4*>(&g[(size_t)s0 * 64 + q]);
      acc.x += (float)v0.x; acc.y += (float)v0.y; acc.z += (float)v0.z; acc.w += (float)v0.w;
    }
    dvv = dinv[node];
    float4 bv = *reinterpret_cast<const float4*>(&b1[q]);
    o.x = acc.x * dvv + bv.x; o.y = acc.y * dvv + bv.y;
    o.z = acc.z * dvv + bv.z; o.w = acc.w * dvv + bv.w;
    o.x = o.x > 0.f ? o.x : 0.01f * o.x;
    o.y = o.y > 0.f ? o.y : 0.01f * o.y;
    o.z = o.z > 0.f ? o.z : 0.01f * o.z;
    o.w = o.w > 0.f ? o.w : 0.01f * o.w;
  }
  *reinterpret_cast<float4*>(&hidS[nl * 68 + q]) = o;
  __syncthreads();

  // phase 2: mini-GEMM. lane j of node nl computes cols j, j+16, (j<8: j+32).
  int j = t & 15;
  float a0 = 0.f, a1 = 0.f, a2 = 0.f;
  const float* hrow = &hidS[nl * 68];
  #pragma unroll
  for (int k4 = 0; k4 < 16; ++k4) {
    float4 hv = *reinterpret_cast<const float4*>(&hrow[k4 * 4]);
    int kb = k4 * 4 * 40 + j;
    a0 = fmaf(hv.x, Ws2[kb + 0 * 40],      a0);
    a1 = fmaf(hv.x, Ws2[kb + 0 * 40 + 16], a1);
    a2 = fmaf(hv.x, Ws2[kb + 0 * 40 + 32], a2);
    a0 = fmaf(hv.y, Ws2[kb + 1 * 40],      a0);
    a1 = fmaf(hv.y, Ws2[kb + 1 * 40 + 16], a1);
    a2 = fmaf(hv.y, Ws2[kb + 1 * 40 + 32], a2);
    a0 = fmaf(hv.z, Ws2[kb + 2 * 40],      a0);
    a1 = fmaf(hv.z, Ws2[kb + 2 * 40 + 16], a1);
    a2 = fmaf(hv.z, Ws2[kb + 2 * 40 + 32], a2);
    a0 = fmaf(hv.w, Ws2[kb + 3 * 40],      a0);
    a1 = fmaf(hv.w, Ws2[kb + 3 * 40 + 16], a1);
    a2 = fmaf(hv.w, Ws2[kb + 3 * 40 + 32], a2);
  }
  if (valid) {
    g2[(size_t)node * 40 + j]      = (_Float16)(a0 * dvv);
    g2[(size_t)node * 40 + j + 16] = (_Float16)(a1 * dvv);
    if (j < 8)
      g2[(size_t)node * 40 + j + 32] = (_Float16)(a2 * dvv);
  }
}

// ---------------- gather layer2 (fused epilogue): out = (g2[c]+Σg2[src])·dinv[c] + b2 ----------------
__global__ __launch_bounds__(320) void k_gather2(const int* __restrict__ row_ptr, const int* __restrict__ src,
                                                 const _Float16* __restrict__ g2, const float* __restrict__ dinv,
                                                 const float* __restrict__ b2, float* __restrict__ out) {
  int t = threadIdx.x;
  int local = t / 10;
  int grp = t - local * 10;
  int node = blockIdx.x * 32 + local;
  if (node >= NN) return;
  int q = grp * 4;
  int beg = row_ptr[node], end = row_ptr[node + 1];
  half4 sv = *reinterpret_cast<const half4*>(&g2[(size_t)node * 40 + q]);  // self loop
  float4 acc = make_float4((float)sv.x, (float)sv.y, (float)sv.z, (float)sv.w);
  int e = beg;
  for (; e + 3 < end; e += 4) {
    int s0 = src[e], s1 = src[e + 1], s2 = src[e + 2], s3 = src[e + 3];
    half4 v0 = *reinterpret_cast<const half4*>(&g2[(size_t)s0 * 40 + q]);
    half4 v1 = *reinterpret_cast<const half4*>(&g2[(size_t)s1 * 40 + q]);
    half4 v2 = *reinterpret_cast<const half4*>(&g2[(size_t)s2 * 40 + q]);
    half4 v3 = *reinterpret_cast<const half4*>(&g2[(size_t)s3 * 40 + q]);
    acc.x += ((float)v0.x + (float)v1.x) + ((float)v2.x + (float)v3.x);
    acc.y += ((float)v0.y + (float)v1.y) + ((float)v2.y + (float)v3.y);
    acc.z += ((float)v0.z + (float)v1.z) + ((float)v2.z + (float)v3.z);
    acc.w += ((float)v0.w + (float)v1.w) + ((float)v2.w + (float)v3.w);
  }
  for (; e < end; ++e) {
    int s0 = src[e];
    half4 v0 = *reinterpret_cast<const half4*>(&g2[(size_t)s0 * 40 + q]);
    acc.x += (float)v0.x; acc.y += (float)v0.y; acc.z += (float)v0.z; acc.w += (float)v0.w;
  }
  float dv = dinv[node];
  float4 bv = *reinterpret_cast<const float4*>(&b2[q]);
  float4 o;
  o.x = acc.x * dv + bv.x; o.y = acc.y * dv + bv.y;
  o.z = acc.z * dv + bv.z; o.w = acc.w * dv + bv.w;
  *reinterpret_cast<float4*>(&out[(size_t)node * 40 + q]) = o;
}

extern "C" void kernel_launch(void* const* d_in, const int* in_sizes, int n_in,
                              void* d_out, int out_size, void* d_ws, size_t ws_size,
                              hipStream_t stream) {
  const float* x  = (const float*)d_in[0];
  const int*   ei = (const int*)d_in[1];       // row = ei, col = ei + EE
  const float* W1 = (const float*)d_in[2];
  const float* b1 = (const float*)d_in[3];
  const float* W2 = (const float*)d_in[4];
  const float* b2 = (const float*)d_in[5];
  float* out = (float*)d_out;

  const int* row = ei;
  const int* col = ei + EE;

  // workspace layout (4B units unless noted)
  float* ws      = (float*)d_ws;
  float* dinv    = ws;                          // 100352 f32
  int*   row_ptr = (int*)(ws + 100352);         // 100352 (needs NN+1)
  int*   bptr    = row_ptr + 100352;            // 512 (needs NB+1)
  int*   bcnt    = bptr + 512;                  // 512
  int*   bcur    = bcnt + 512;                  // 512
  int*   src     = bcur + 512;                  // 1200128
  _Float16* g1   = (_Float16*)(src + 1200128);  // 6.4M halves = 12.8 MB
  _Float16* g2   = (_Float16*)((char*)g1 + 12800000);  // 4M halves = 8 MB
  int*   binned  = (int*)g1;                    // 1.2M ints, aliases g1 (dead before gemm1)

  // CSR build (bucketed counting sort) + dinv
  hipMemsetAsync(bcnt, 0, 512 * sizeof(int), stream);
  k_binhist<<<BIN_BLK, 256, 0, stream>>>(col, bcnt);
  k_binscan<<<1, 512, 0, stream>>>(bcnt, bptr, bcur, row_ptr);
  k_binfill<<<BIN_BLK, 256, 0, stream>>>(row, col, bcur, binned);
  k_build2 <<<NB, 256, 0, stream>>>(binned, bptr, row_ptr, src, dinv);

  // layer 1 GEMM
  k_gemm1  <<<(NN + 63) / 64, 256, 0, stream>>>(x, W1, dinv, g1);
  // gather1 + fused layer-2 GEMM
  k_gather1f<<<(NN + 15) / 16, 256, 0, stream>>>(row_ptr, src, g1, dinv, b1, W2, g2);
  // layer 2 gather
  k_gather2<<<(NN + 31) / 32, 320, 0, stream>>>(row_ptr, src, g2, dinv, b2, out);
}

// Round 14
// 215.911 us; speedup vs baseline: 1.0751x; 1.0751x over previous
//
#include <hip/hip_runtime.h>

#define NN 100000
#define EE 1200000
#define NB 391          // ceil(NN/256) buckets of 256 nodes
#define BSLOT 4096      // fixed slots per bucket (mean 3069, sigma 55 -> 18-sigma headroom)
#define EPB 4096        // edges per block in binfill
#define BIN_BLK 293     // ceil(EE/EPB)

typedef _Float16 half4 __attribute__((ext_vector_type(4)));
typedef _Float16 half8 __attribute__((ext_vector_type(8)));
typedef float    f32x4 __attribute__((ext_vector_type(4)));

// ---------------- init bucket cursors to fixed bases ----------------
__global__ __launch_bounds__(256) void k_init(int* __restrict__ bcur) {
  int i = blockIdx.x * 256 + threadIdx.x;
  if (i < NB) bcur[i] = i << 12;     // b * BSLOT
}

// ---------------- single-pass bucket fill: binned[p] = (row<<8)|(col&255) ----------------
__global__ __launch_bounds__(256) void k_binfill(const int* __restrict__ row, const int* __restrict__ col,
                                                 int* __restrict__ bcur, int* __restrict__ binned) {
  __shared__ int lh[NB];
  __shared__ int lbase[NB];
  int t = threadIdx.x;
  for (int i = t; i < NB; i += 256) lh[i] = 0;
  __syncthreads();
  int base = blockIdx.x * EPB;
  #pragma unroll
  for (int i = 0; i < 16; ++i) {
    int e = base + i * 256 + t;
    if (e < EE) atomicAdd(&lh[col[e] >> 8], 1);
  }
  __syncthreads();
  // reserve contiguous global ranges per bucket (bases are pre-strided b*BSLOT)
  for (int i = t; i < NB; i += 256) {
    int v = lh[i];
    lbase[i] = v ? atomicAdd(&bcur[i], v) : 0;
  }
  __syncthreads();
  for (int i = t; i < NB; i += 256) lh[i] = 0;   // reuse as local cursor
  __syncthreads();
  #pragma unroll
  for (int i = 0; i < 16; ++i) {
    int e = base + i * 256 + t;
    if (e < EE) {
      int c = col[e];
      int b = c >> 8;
      int p = lbase[b] + atomicAdd(&lh[b], 1);
      binned[p] = (row[e] << 8) | (c & 255);
    }
  }
}

// ---------------- per-bucket CSR build: node_range (beg,end), src, dinv ----------------
__global__ __launch_bounds__(256) void k_build2(const int* __restrict__ binned, const int* __restrict__ bcur,
                                                int2* __restrict__ node_range, int* __restrict__ src,
                                                float* __restrict__ dinv) {
  __shared__ int cnt[256];
  __shared__ int sm[256];
  __shared__ int cur[256];
  int t = threadIdx.x;
  int b = blockIdx.x;
  int nb0 = b << 8;
  int nnode = NN - nb0 < 256 ? NN - nb0 : 256;
  int ebeg = b << 12;                 // fixed bucket base
  int eend = bcur[b];                 // base + bucket count
  cnt[t] = 0;
  __syncthreads();
  for (int e = ebeg + t; e < eend; e += 256)
    atomicAdd(&cnt[binned[e] & 255], 1);
  __syncthreads();
  int v = cnt[t];
  sm[t] = v;
  __syncthreads();
  for (int off = 1; off < 256; off <<= 1) {
    int u = (t >= off) ? sm[t - off] : 0;
    __syncthreads();
    sm[t] += u;
    __syncthreads();
  }
  int excl = sm[t] - v;
  if (t < nnode) {
    node_range[nb0 + t] = make_int2(ebeg + excl, ebeg + excl + v);
    dinv[nb0 + t] = rsqrtf((float)v + 1.0f);   // deg = in-count + self-loop
  }
  cur[t] = excl;
  __syncthreads();
  for (int e = ebeg + t; e < eend; e += 256) {
    int rc = binned[e];
    int cl = rc & 255;
    int p = ebeg + atomicAdd(&cur[cl], 1);
    src[p] = rc >> 8;
  }
}

// ---------------- GEMM1 (MFMA f16): g = fp16((x @ W1) * dinv[row]) ----------------
// 64 rows/block, 4 waves; wave w -> rows w*16..w*16+15, all 64 cols (4 n-tiles), K=128 (4 k-steps).
__global__ __launch_bounds__(256) void k_gemm1(const float* __restrict__ x, const float* __restrict__ W,
                                               const float* __restrict__ dinv, _Float16* __restrict__ g) {
  __shared__ _Float16 xh[64 * 136];   // 17.4 KB
  __shared__ _Float16 Wt[64 * 136];   // 17.4 KB, transposed: Wt[n][k]
  const int t = threadIdx.x;
  const int row0 = blockIdx.x * 64;

  // stage W transposed -> f16
  #pragma unroll
  for (int p = 0; p < 8; ++p) {
    int idx = t + p * 256;
    int k = idx >> 4;
    int n4 = (idx & 15) << 2;
    float4 v = *reinterpret_cast<const float4*>(&W[k * 64 + n4]);
    Wt[(n4 + 0) * 136 + k] = (_Float16)v.x;
    Wt[(n4 + 1) * 136 + k] = (_Float16)v.y;
    Wt[(n4 + 2) * 136 + k] = (_Float16)v.z;
    Wt[(n4 + 3) * 136 + k] = (_Float16)v.w;
  }
  // stage x rows -> f16
  #pragma unroll
  for (int p = 0; p < 4; ++p) {
    int idx = t + p * 256;          // 0..1023
    int r = idx >> 4;               // 0..63
    int k8 = idx & 15;              // 8-half group
    int grow = row0 + r;
    half8 h = {0, 0, 0, 0, 0, 0, 0, 0};
    if (grow < NN) {
      float4 a0 = *reinterpret_cast<const float4*>(&x[(size_t)grow * 128 + k8 * 8]);
      float4 a1 = *reinterpret_cast<const float4*>(&x[(size_t)grow * 128 + k8 * 8 + 4]);
      h[0] = (_Float16)a0.x; h[1] = (_Float16)a0.y; h[2] = (_Float16)a0.z; h[3] = (_Float16)a0.w;
      h[4] = (_Float16)a1.x; h[5] = (_Float16)a1.y; h[6] = (_Float16)a1.z; h[7] = (_Float16)a1.w;
    }
    *reinterpret_cast<half8*>(&xh[r * 136 + k8 * 8]) = h;
  }
  __syncthreads();

  const int w = t >> 6;      // wave 0..3
  const int l = t & 63;
  const int lrow = l & 15;   // A row / B col / C col
  const int kg = l >> 4;     // k-group 0..3

  f32x4 z = {0.0f, 0.0f, 0.0f, 0.0f};
  f32x4 acc[4];
  acc[0] = z; acc[1] = z; acc[2] = z; acc[3] = z;

  const _Float16* xb = &xh[(w * 16 + lrow) * 136 + kg * 8];
  #pragma unroll
  for (int s = 0; s < 4; ++s) {     // K=128, 32 per step
    half8 a = *reinterpret_cast<const half8*>(xb + s * 32);
    #pragma unroll
    for (int nt = 0; nt < 4; ++nt) {
      half8 b = *reinterpret_cast<const half8*>(&Wt[(nt * 16 + lrow) * 136 + kg * 8 + s * 32]);
      acc[nt] = __builtin_amdgcn_mfma_f32_16x16x32_f16(a, b, acc[nt], 0, 0, 0);
    }
  }

  // epilogue: C/D layout col=lane&15, row=(lane>>4)*4+reg (m89-verified)
  float dv[4];
  #pragma unroll
  for (int r = 0; r < 4; ++r) {
    int grow = row0 + w * 16 + kg * 4 + r;
    dv[r] = (grow < NN) ? dinv[grow] : 0.0f;
  }
  #pragma unroll
  for (int nt = 0; nt < 4; ++nt)
    #pragma unroll
    for (int r = 0; r < 4; ++r) {
      int grow = row0 + w * 16 + kg * 4 + r;
      if (grow < NN)
        g[(size_t)grow * 64 + nt * 16 + lrow] = (_Float16)(acc[nt][r] * dv[r]);
    }
}

// ---------------- gather layer1 (fused epilogue): hid = fp16(lrelu((g[c]+Σg[src])·dinv[c] + b1)) ----------------
__global__ __launch_bounds__(256) void k_gather1(const int2* __restrict__ node_range, const int* __restrict__ src,
                                                 const _Float16* __restrict__ g, const float* __restrict__ dinv,
                                                 const float* __restrict__ b1, _Float16* __restrict__ hid) {
  int t = threadIdx.x;
  int node = blockIdx.x * 16 + (t >> 4);
  if (node >= NN) return;
  int q = (t & 15) << 2;
  int2 rng = node_range[node];
  int beg = rng.x, end = rng.y;
  half4 sv = *reinterpret_cast<const half4*>(&g[(size_t)node * 64 + q]);   // self loop
  float4 acc = make_float4((float)sv.x, (float)sv.y, (float)sv.z, (float)sv.w);
  int e = beg;
  for (; e + 3 < end; e += 4) {
    int s0 = src[e], s1 = src[e + 1], s2 = src[e + 2], s3 = src[e + 3];
    half4 v0 = *reinterpret_cast<const half4*>(&g[(size_t)s0 * 64 + q]);
    half4 v1 = *reinterpret_cast<const half4*>(&g[(size_t)s1 * 64 + q]);
    half4 v2 = *reinterpret_cast<const half4*>(&g[(size_t)s2 * 64 + q]);
    half4 v3 = *reinterpret_cast<const half4*>(&g[(size_t)s3 * 64 + q]);
    acc.x += ((float)v0.x + (float)v1.x) + ((float)v2.x + (float)v3.x);
    acc.y += ((float)v0.y + (float)v1.y) + ((float)v2.y + (float)v3.y);
    acc.z += ((float)v0.z + (float)v1.z) + ((float)v2.z + (float)v3.z);
    acc.w += ((float)v0.w + (float)v1.w) + ((float)v2.w + (float)v3.w);
  }
  for (; e < end; ++e) {
    int s0 = src[e];
    half4 v0 = *reinterpret_cast<const half4*>(&g[(size_t)s0 * 64 + q]);
    acc.x += (float)v0.x; acc.y += (float)v0.y; acc.z += (float)v0.z; acc.w += (float)v0.w;
  }
  float dv = dinv[node];
  float4 bv = *reinterpret_cast<const float4*>(&b1[q]);
  float4 o;
  o.x = acc.x * dv + bv.x; o.y = acc.y * dv + bv.y;
  o.z = acc.z * dv + bv.z; o.w = acc.w * dv + bv.w;
  o.x = o.x > 0.f ? o.x : 0.01f * o.x;
  o.y = o.y > 0.f ? o.y : 0.01f * o.y;
  o.z = o.z > 0.f ? o.z : 0.01f * o.z;
  o.w = o.w > 0.f ? o.w : 0.01f * o.w;
  half4 ho;
  ho.x = (_Float16)o.x; ho.y = (_Float16)o.y; ho.z = (_Float16)o.z; ho.w = (_Float16)o.w;
  *reinterpret_cast<half4*>(&hid[(size_t)node * 64 + q]) = ho;
}

// ---------------- GEMM2 (MFMA f16): g2 = fp16((hid @ W2) * dinv[row]), N=40 padded to 48 ----------------
__global__ __launch_bounds__(256) void k_gemm2(const _Float16* __restrict__ hid, const float* __restrict__ W,
                                               const float* __restrict__ dinv, _Float16* __restrict__ g2) {
  __shared__ _Float16 xh[64 * 72];   // 9.2 KB
  __shared__ _Float16 Wt[48 * 72];   // 6.9 KB, transposed + zero-padded cols 40..47
  const int t = threadIdx.x;
  const int row0 = blockIdx.x * 64;

  #pragma unroll
  for (int p = 0; p < 12; ++p) {     // 48*64 = 3072 slots
    int idx = t + p * 256;
    int n = idx >> 6, k = idx & 63;
    _Float16 v = (_Float16)0.0f;
    if (n < 40) v = (_Float16)W[k * 40 + n];
    Wt[n * 72 + k] = v;
  }
  #pragma unroll
  for (int p = 0; p < 2; ++p) {      // 64 rows x 8 half8-groups
    int idx = t + p * 256;
    int r = idx >> 3, k8 = idx & 7;
    int grow = row0 + r;
    half8 h = {0, 0, 0, 0, 0, 0, 0, 0};
    if (grow < NN) h = *reinterpret_cast<const half8*>(&hid[(size_t)grow * 64 + k8 * 8]);
    *reinterpret_cast<half8*>(&xh[r * 72 + k8 * 8]) = h;
  }
  __syncthreads();

  const int w = t >> 6;
  const int l = t & 63;
  const int lrow = l & 15;
  const int kg = l >> 4;

  f32x4 z = {0.0f, 0.0f, 0.0f, 0.0f};
  f32x4 acc[3];
  acc[0] = z; acc[1] = z; acc[2] = z;

  const _Float16* xb = &xh[(w * 16 + lrow) * 72 + kg * 8];
  #pragma unroll
  for (int s = 0; s < 2; ++s) {      // K=64, 32 per step
    half8 a = *reinterpret_cast<const half8*>(xb + s * 32);
    #pragma unroll
    for (int nt = 0; nt < 3; ++nt) {
      half8 b = *reinterpret_cast<const half8*>(&Wt[(nt * 16 + lrow) * 72 + kg * 8 + s * 32]);
      acc[nt] = __builtin_amdgcn_mfma_f32_16x16x32_f16(a, b, acc[nt], 0, 0, 0);
    }
  }

  float dv[4];
  #pragma unroll
  for (int r = 0; r < 4; ++r) {
    int grow = row0 + w * 16 + kg * 4 + r;
    dv[r] = (grow < NN) ? dinv[grow] : 0.0f;
  }
  #pragma unroll
  for (int nt = 0; nt < 3; ++nt) {
    int colv = nt * 16 + lrow;
    #pragma unroll
    for (int r = 0; r < 4; ++r) {
      int grow = row0 + w * 16 + kg * 4 + r;
      if (grow < NN && colv < 40)
        g2[(size_t)grow * 40 + colv] = (_Float16)(acc[nt][r] * dv[r]);
    }
  }
}

// ---------------- gather layer2 (fused epilogue): out = (g2[c]+Σg2[src])·dinv[c] + b2 ----------------
__global__ __launch_bounds__(320) void k_gather2(const int2* __restrict__ node_range, const int* __restrict__ src,
                                                 const _Float16* __restrict__ g2, const float* __restrict__ dinv,
                                                 const float* __restrict__ b2, float* __restrict__ out) {
  int t = threadIdx.x;
  int local = t / 10;
  int grp = t - local * 10;
  int node = blockIdx.x * 32 + local;
  if (node >= NN) return;
  int q = grp * 4;
  int2 rng = node_range[node];
  int beg = rng.x, end = rng.y;
  half4 sv = *reinterpret_cast<const half4*>(&g2[(size_t)node * 40 + q]);  // self loop
  float4 acc = make_float4((float)sv.x, (float)sv.y, (float)sv.z, (float)sv.w);
  int e = beg;
  for (; e + 3 < end; e += 4) {
    int s0 = src[e], s1 = src[e + 1], s2 = src[e + 2], s3 = src[e + 3];
    half4 v0 = *reinterpret_cast<const half4*>(&g2[(size_t)s0 * 40 + q]);
    half4 v1 = *reinterpret_cast<const half4*>(&g2[(size_t)s1 * 40 + q]);
    half4 v2 = *reinterpret_cast<const half4*>(&g2[(size_t)s2 * 40 + q]);
    half4 v3 = *reinterpret_cast<const half4*>(&g2[(size_t)s3 * 40 + q]);
    acc.x += ((float)v0.x + (float)v1.x) + ((float)v2.x + (float)v3.x);
    acc.y += ((float)v0.y + (float)v1.y) + ((float)v2.y + (float)v3.y);
    acc.z += ((float)v0.z + (float)v1.z) + ((float)v2.z + (float)v3.z);
    acc.w += ((float)v0.w + (float)v1.w) + ((float)v2.w + (float)v3.w);
  }
  for (; e < end; ++e) {
    int s0 = src[e];
    half4 v0 = *reinterpret_cast<const half4*>(&g2[(size_t)s0 * 40 + q]);
    acc.x += (float)v0.x; acc.y += (float)v0.y; acc.z += (float)v0.z; acc.w += (float)v0.w;
  }
  float dv = dinv[node];
  float4 bv = *reinterpret_cast<const float4*>(&b2[q]);
  float4 o;
  o.x = acc.x * dv + bv.x; o.y = acc.y * dv + bv.y;
  o.z = acc.z * dv + bv.z; o.w = acc.w * dv + bv.w;
  *reinterpret_cast<float4*>(&out[(size_t)node * 40 + q]) = o;
}

extern "C" void kernel_launch(void* const* d_in, const int* in_sizes, int n_in,
                              void* d_out, int out_size, void* d_ws, size_t ws_size,
                              hipStream_t stream) {
  const float* x  = (const float*)d_in[0];
  const int*   ei = (const int*)d_in[1];       // row = ei, col = ei + EE
  const float* W1 = (const float*)d_in[2];
  const float* b1 = (const float*)d_in[3];
  const float* W2 = (const float*)d_in[4];
  const float* b2 = (const float*)d_in[5];
  float* out = (float*)d_out;

  const int* row = ei;
  const int* col = ei + EE;

  // workspace layout (4B units unless noted)
  float* ws        = (float*)d_ws;
  float* dinv      = ws;                            // 100352 f32
  int2*  node_range= (int2*)(ws + 100352);          // NN int2 = 200704 ints
  int*   bcur      = (int*)(ws + 301056);           // 512
  int*   src       = bcur + 512;                    // NB*BSLOT = 1601536 (gapped)
  _Float16* g1     = (_Float16*)(ws + 1903104);     // 6.4M halves = 12.8 MB
  _Float16* hid    = (_Float16*)((char*)g1 + 12800000);  // 6.4M halves = 12.8 MB
  _Float16* g2     = g1;                            // reuse (g1 dead after gather1); 8 MB
  int*   binned    = (int*)g1;                      // NB*BSLOT ints = 6.4 MB, aliases g1

  // single-pass CSR build (fixed-stride buckets) + dinv
  k_init   <<<2, 256, 0, stream>>>(bcur);
  k_binfill<<<BIN_BLK, 256, 0, stream>>>(row, col, bcur, binned);
  k_build2 <<<NB, 256, 0, stream>>>(binned, bcur, node_range, src, dinv);

  // layer 1
  k_gemm1  <<<(NN + 63) / 64, 256, 0, stream>>>(x, W1, dinv, g1);
  k_gather1<<<(NN + 15) / 16, 256, 0, stream>>>(node_range, src, g1, dinv, b1, hid);

  // layer 2
  k_gemm2  <<<(NN + 63) / 64, 256, 0, stream>>>(hid, W2, dinv, g2);
  k_gather2<<<(NN + 31) / 32, 320, 0, stream>>>(node_range, src, g2, dinv, b2, out);
}